// Round 7
// baseline (191.516 us; speedup 1.0000x reference)
//
#include <hip/hip_runtime.h>

#define B_ 8
#define C_ 256
#define N_ 4096
#define HD_ 32

#define ALPHA_ 0.36787944117144233f   // elu(-1)+1 = e^-1
#define BETAS_ (2.0f - ALPHA_)        // spike value 2.0 = ALPHA_ + BETAS_
#define SCALE_ 0.17677669529663687f   // 32^-0.5

typedef _Float16 f16;
typedef _Float16 f16x8 __attribute__((ext_vector_type(8)));
typedef float f32x4 __attribute__((ext_vector_type(4)));
typedef __attribute__((address_space(3))) f16 lds_f16;

#define MFMA(a,b,c) __builtin_amdgcn_mfma_f32_16x16x32_f16((a),(b),(c),0,0,0)

#define GLDS(g, l) __builtin_amdgcn_global_load_lds( \
    (const __attribute__((address_space(1))) void*)(g), \
    (__attribute__((address_space(3))) void*)(l), 16, 0, 0)

// inline-asm LDS read: opaque to compiler -> no conservative vmcnt(0) wait
#define DSR(dst, off) asm volatile("ds_read_b128 %0, %1" : "=v"(dst) : "v"(off))

// ---------------------------------------------------------------------------
// K0a: transpose + split X: x[b][i][n] f32 -> XTh/XTl[b][n][i] f16
// ---------------------------------------------------------------------------
__global__ __launch_bounds__(256) void transpose_split(
    const float* __restrict__ x, f16* __restrict__ XTh, f16* __restrict__ XTl)
{
    __shared__ float tile[32][257];
    int t = threadIdx.x;
    int b = blockIdx.z, i0 = blockIdx.y * 32, n0 = blockIdx.x * 256;
    const float* src = x + ((size_t)b * C_ + i0) * N_ + n0;
    int r = t >> 3, c0 = (t & 7) * 32;
    #pragma unroll
    for (int q = 0; q < 8; ++q) {
        float4 v = *reinterpret_cast<const float4*>(src + (size_t)r * N_ + c0 + q * 4);
        tile[r][c0 + q*4 + 0] = v.x; tile[r][c0 + q*4 + 1] = v.y;
        tile[r][c0 + q*4 + 2] = v.z; tile[r][c0 + q*4 + 3] = v.w;
    }
    __syncthreads();
    size_t ob = ((size_t)b * N_ + n0 + t) * C_ + i0;
    #pragma unroll
    for (int q = 0; q < 4; ++q) {
        f16x8 hv, lv;
        #pragma unroll
        for (int j = 0; j < 8; ++j) {
            float v = tile[q*8 + j][t];
            f16 h = (f16)v;
            hv[j] = h;
            lv[j] = (f16)(v - (float)h);
        }
        *reinterpret_cast<f16x8*>(XTh + ob + q*8) = hv;
        *reinterpret_cast<f16x8*>(XTl + ob + q*8) = lv;
    }
}

// ---------------------------------------------------------------------------
// K0b: split weights into Wc[1024][256]: rows 0-255 Wq, 256-511 Wk, 512-767 Wv,
// 768-1023 Wo.
// ---------------------------------------------------------------------------
__global__ __launch_bounds__(256) void weight_split(
    const float* __restrict__ Wq, const float* __restrict__ Wk,
    const float* __restrict__ Wv, const float* __restrict__ Wo,
    f16* __restrict__ Wch, f16* __restrict__ Wcl)
{
    int idx4 = (blockIdx.x * 256 + threadIdx.x) * 4;   // 262144 elems
    int o = idx4 >> 8, i = idx4 & 255;
    const float* src = (o < 256) ? (Wq + (size_t)o * 256)
                     : (o < 512) ? (Wk + (size_t)(o - 256) * 256)
                     : (o < 768) ? (Wv + (size_t)(o - 512) * 256)
                                 : (Wo + (size_t)(o - 768) * 256);
    float4 v = *reinterpret_cast<const float4*>(src + i);
    f16 h0 = (f16)v.x, h1 = (f16)v.y, h2 = (f16)v.z, h3 = (f16)v.w;
    f16 hh[4] = { h0, h1, h2, h3 };
    f16 ll[4] = { (f16)(v.x - (float)h0), (f16)(v.y - (float)h1),
                  (f16)(v.z - (float)h2), (f16)(v.w - (float)h3) };
    *reinterpret_cast<uint2*>(Wch + idx4) = *reinterpret_cast<uint2*>(hh);
    *reinterpret_cast<uint2*>(Wcl + idx4) = *reinterpret_cast<uint2*>(ll);
}

// ---------------------------------------------------------------------------
// MFMA GEMM: out[o,n] = sum_i Wc[o,i]*B[n,i].
// FULLP=1: split fp16, 3 MFMA terms (QKV path).  FULLP=0: single fp16 plane.
// Block tile 128o x 128n, K-step 32, 256 threads, 4 waves (2m x 2n),
// wave tile 64x64, acc 4x4 frags.
// A (weights) read DIRECTLY from global per fragment (L1/L2-hot, no LDS).
// B staged in LDS via global_load_lds, 2 buffers x (16KB | 8KB):
//   slots (16B): B_h [0,512) slot r*4+c, B_l [512,1024) (FULLP only)
//   chunk XOR-swizzle c ^ ((r>>1)&3) on gload-src and ds_read (involution).
// Step: loadA(k) -> STAGE(next tile) -> ds_read(cur) -> lgkm(0) -> MFMA
//       (compiler vmcnt drains A only; staging stays in flight) ->
//       vmcnt(0)+s_barrier.
// ---------------------------------------------------------------------------
template<bool LIF, bool FULLP>
__global__ __launch_bounds__(256, 3) void mfma_gemm(
    const f16* __restrict__ Wch, const f16* __restrict__ Wcl,
    const f16* __restrict__ Bh,  const f16* __restrict__ Bl,
    const float* __restrict__ mq, const float* __restrict__ mk2,
    const float* __restrict__ mv,
    float* __restrict__ o0, float* __restrict__ o1, float* __restrict__ o2)
{
    constexpr int SLOTS = FULLP ? 1024 : 512;   // 16B slots per buffer
    constexpr int NGL   = FULLP ? 4 : 2;        // gload_lds per thread per step

    int gid = blockIdx.x;
    int b = gid & 7, slot = gid >> 3;           // batch -> XCD
    int conv, oTi, nt;
    if (LIF) { conv = slot % 3; int rest = slot / 3; oTi = rest & 1; nt = rest >> 1; }
    else     { conv = 0;        oTi = slot & 1;      nt = slot >> 1; }
    int wRow0 = (LIF ? conv * 256 : 768) + oTi * 128;
    int chOut0 = oTi * 128;
    int nT = nt * 128;

    const float* memP = nullptr; float* outP;
    if (LIF) {
        memP = (conv == 0) ? mq : (conv == 1) ? mk2 : mv;
        outP = (conv == 0) ? o0 : (conv == 1) ? o1 : o2;
    } else outP = o0;

    __shared__ __align__(16) f16 smem[2][SLOTS * 8];

    int t = threadIdx.x;
    int wid = t >> 6, lane = t & 63;
    int wm = wid >> 1, wn = wid & 1;
    int lr = lane & 15, g = lane >> 4;

    // B staging global pointers (k=0)
    const f16* gB[NGL];
    #pragma unroll
    for (int i = 0; i < NGL; ++i) {
        int s = i * 256 + t;
        int sp = s & 511;
        int r = sp >> 2, c = (sp & 3) ^ ((r >> 1) & 3);
        const f16* plane = (s < 512) ? Bh : Bl;
        gB[i] = plane + ((size_t)b * N_ + nT + r) * 256 + c * 8;
    }

    // A fragment offsets (direct-global): row = ..+lr, k-chunk = g
    int aOff[4];
    #pragma unroll
    for (int m = 0; m < 4; ++m)
        aOff[m] = (wRow0 + wm * 64 + m * 16 + lr) * 256 + g * 8;

    // B fragment LDS byte offsets
    unsigned lbase = (unsigned)(size_t)(lds_f16*)&smem[0][0];
    unsigned offB[4];
    #pragma unroll
    for (int n = 0; n < 4; ++n) {
        int r = wn * 64 + n * 16 + lr;
        offB[n] = (unsigned)((r * 4 + (g ^ ((r >> 1) & 3))) * 16);
    }

    f32x4 acc[4][4];
    #pragma unroll
    for (int m = 0; m < 4; ++m)
        #pragma unroll
        for (int n = 0; n < 4; ++n) acc[m][n] = (f32x4){0.f, 0.f, 0.f, 0.f};

    // prologue: stage K-tile 0 into buffer 0 (full drain once)
    #pragma unroll
    for (int i = 0; i < NGL; ++i)
        GLDS(gB[i], &smem[0][(i * 256 + t) * 8]);
    __syncthreads();

    #pragma unroll
    for (int ks = 0; ks < 8; ++ks) {
        const int cur = ks & 1;
        const int k0 = ks * 32;
        // A fragments for THIS step (oldest in vmcnt queue)
        f16x8 ah[4], al[4];
        #pragma unroll
        for (int m = 0; m < 4; ++m) {
            ah[m] = *reinterpret_cast<const f16x8*>(Wch + aOff[m] + k0);
            if (FULLP) al[m] = *reinterpret_cast<const f16x8*>(Wcl + aOff[m] + k0);
        }
        __builtin_amdgcn_sched_barrier(0);
        // stage NEXT tile (stays in flight through the MFMA phase)
        if (ks < 7) {
            #pragma unroll
            for (int i = 0; i < NGL; ++i)
                GLDS(gB[i] + k0 + 32, &smem[cur ^ 1][(i * 256 + t) * 8]);
        }
        // B fragments from current buffer
        const unsigned base = lbase + (unsigned)(cur * (SLOTS * 16));
        f16x8 bhf[4], blf[4];
        #pragma unroll
        for (int n = 0; n < 4; ++n) {
            DSR(bhf[n], base + offB[n]);
            if (FULLP) DSR(blf[n], base + offB[n] + 8192);
        }
        asm volatile("s_waitcnt lgkmcnt(0)" ::: "memory");
        __builtin_amdgcn_sched_barrier(0);
        #pragma unroll
        for (int n = 0; n < 4; ++n)
            #pragma unroll
            for (int m = 0; m < 4; ++m) {
                acc[m][n] = MFMA(ah[m], bhf[n], acc[m][n]);
                if (FULLP) {
                    acc[m][n] = MFMA(ah[m], blf[n], acc[m][n]);
                    acc[m][n] = MFMA(al[m], bhf[n], acc[m][n]);
                }
            }
        __builtin_amdgcn_sched_barrier(0);
        if (ks < 7) {
            asm volatile("s_waitcnt vmcnt(0)" ::: "memory");
            __builtin_amdgcn_s_barrier();
        }
    }

    // epilogue: D layout col = lane&15 (n), row = (lane>>4)*4 + reg (o)
    #pragma unroll
    for (int m = 0; m < 4; ++m) {
        int oLoc = chOut0 + wm * 64 + m * 16 + g * 4;
        #pragma unroll
        for (int n = 0; n < 4; ++n) {
            int nn = nT + wn * 64 + n * 16 + lr;
            #pragma unroll
            for (int r = 0; r < 4; ++r) {
                size_t idx = ((size_t)b * C_ + oLoc + r) * N_ + nn;
                float v = acc[m][n][r];
                if (LIF) {
                    float mm = memP[idx];
                    outP[idx] = 0.5f * mm + v - (mm > 1.0f ? 1.0f : 0.0f);
                } else {
                    outP[idx] = v;
                }
            }
        }
    }
}

// ---------------------------------------------------------------------------
// K2 stage 1: per (bh, n-slice of 512): partial popcounts via 64-bit ballots.
// ---------------------------------------------------------------------------
__global__ __launch_bounds__(256) void kv_stage1(
    const float* __restrict__ Km, const float* __restrict__ Vm,
    int* __restrict__ pkv, int* __restrict__ pck, int* __restrict__ pcv)
{
    int bh = blockIdx.x, sl = blockIdx.y;
    int b = bh >> 3, h = bh & 7;
    const float* Kp = Km + ((size_t)(b * C_ + h * HD_)) * N_ + sl * 512;
    const float* Vp = Vm + ((size_t)(b * C_ + h * HD_)) * N_ + sl * 512;

    __shared__ unsigned long long mk[32][9], mv[32][9];
    int t = threadIdx.x, wave = t >> 6, lane = t & 63;

    for (int r = wave; r < 32; r += 4) {
        const float* kr = Kp + (size_t)r * N_;
        const float* vr = Vp + (size_t)r * N_;
        #pragma unroll
        for (int seg = 0; seg < 2; ++seg) {
            float4 kf = *reinterpret_cast<const float4*>(kr + seg * 256 + lane * 4);
            float4 vf = *reinterpret_cast<const float4*>(vr + seg * 256 + lane * 4);
            unsigned long long k0 = __ballot(kf.x > 1.0f);
            unsigned long long k1 = __ballot(kf.y > 1.0f);
            unsigned long long k2 = __ballot(kf.z > 1.0f);
            unsigned long long k3 = __ballot(kf.w > 1.0f);
            unsigned long long v0 = __ballot(vf.x > 1.0f);
            unsigned long long v1 = __ballot(vf.y > 1.0f);
            unsigned long long v2 = __ballot(vf.z > 1.0f);
            unsigned long long v3 = __ballot(vf.w > 1.0f);
            if (lane == 0) {
                mk[r][seg*4+0] = k0; mk[r][seg*4+1] = k1;
                mk[r][seg*4+2] = k2; mk[r][seg*4+3] = k3;
                mv[r][seg*4+0] = v0; mv[r][seg*4+1] = v1;
                mv[r][seg*4+2] = v2; mv[r][seg*4+3] = v3;
            }
        }
    }
    __syncthreads();

    int base = (bh * 8 + sl);
    int d = t >> 3, e0 = (t & 7) * 4;
    #pragma unroll
    for (int j = 0; j < 4; ++j) {
        int e = e0 + j, P = 0;
        #pragma unroll
        for (int w = 0; w < 8; ++w) P += __popcll(mk[d][w] & mv[e][w]);
        pkv[(size_t)base * 1024 + d * 32 + e] = P;
    }
    if (t < 32) {
        int c = 0;
        #pragma unroll
        for (int w = 0; w < 8; ++w) c += __popcll(mk[t][w]);
        pck[base * 32 + t] = c;
    } else if (t < 64) {
        int dd = t - 32, c = 0;
        #pragma unroll
        for (int w = 0; w < 8; ++w) c += __popcll(mv[dd][w]);
        pcv[base * 32 + dd] = c;
    }
}

// K2 stage 2: reduce 8 slices -> kvp, ksump
__global__ __launch_bounds__(256) void kv_stage2(
    const int* __restrict__ pkv, const int* __restrict__ pck,
    const int* __restrict__ pcv, float* __restrict__ kvp, float* __restrict__ ksump)
{
    int bh = blockIdx.x, t = threadIdx.x;
    __shared__ float ck[32], cv[32];
    if (t < 32) {
        int s = 0;
        #pragma unroll
        for (int sl = 0; sl < 8; ++sl) s += pck[(bh * 8 + sl) * 32 + t];
        ck[t] = (float)s;
    } else if (t < 64) {
        int dd = t - 32, s = 0;
        #pragma unroll
        for (int sl = 0; sl < 8; ++sl) s += pcv[(bh * 8 + sl) * 32 + dd];
        cv[dd] = (float)s;
    }
    __syncthreads();
    int d = t >> 3, e0 = (t & 7) * 4;
    #pragma unroll
    for (int j = 0; j < 4; ++j) {
        int e = e0 + j, P = 0;
        #pragma unroll
        for (int sl = 0; sl < 8; ++sl) P += pkv[(size_t)(bh * 8 + sl) * 1024 + d * 32 + e];
        float skv = 2.0f * (float)P - ck[d];
        float sv  = 2.0f * cv[e] - 4096.0f;
        kvp[(size_t)bh * 1024 + d * 32 + e] = ALPHA_ * sv + BETAS_ * skv;
    }
    if ((t & 7) == 0)
        ksump[bh * 32 + d] = ALPHA_ * 4096.0f + BETAS_ * ck[d];
}

// ---------------------------------------------------------------------------
// K3: att = SCALE*(q.kv)/(q.ksum+1e-6), output fp16 ATh [b][n][c]
// (single plane: Wo path tolerates ~2^-11 relative error post-BN)
// ---------------------------------------------------------------------------
__global__ __launch_bounds__(256) void att_kernel(
    const float* __restrict__ Qm, const float* __restrict__ kvp,
    const float* __restrict__ ksump, f16* __restrict__ ATh)
{
    int bh = blockIdx.y; int b = bh >> 3, h = bh & 7;
    int n0 = blockIdx.x * 256;
    const float* Qp = Qm + ((size_t)(b * C_ + h * HD_)) * N_;

    __shared__ float qs[32][260];
    int t = threadIdx.x;
    {
        int r  = t >> 3, c0 = (t & 7) * 32;
        #pragma unroll
        for (int q4 = 0; q4 < 8; ++q4) {
            float4 v = *reinterpret_cast<const float4*>(&Qp[(size_t)r * N_ + n0 + c0 + q4 * 4]);
            qs[r][c0 + q4*4 + 0] = (v.x > 1.0f) ? 2.0f : ALPHA_;
            qs[r][c0 + q4*4 + 1] = (v.y > 1.0f) ? 2.0f : ALPHA_;
            qs[r][c0 + q4*4 + 2] = (v.z > 1.0f) ? 2.0f : ALPHA_;
            qs[r][c0 + q4*4 + 3] = (v.w > 1.0f) ? 2.0f : ALPHA_;
        }
    }
    __syncthreads();

    float q[32];
    #pragma unroll
    for (int d2 = 0; d2 < 32; ++d2) q[d2] = qs[d2][t];

    const float* ksb = ksump + bh * 32;
    float den = 1e-6f;
    #pragma unroll
    for (int d2 = 0; d2 < 32; ++d2) den += q[d2] * ksb[d2];
    float rden = SCALE_ / den;

    const float* kvb = kvp + (size_t)bh * 1024;
    size_t ob = ((size_t)b * N_ + n0 + t) * C_ + h * HD_;
    #pragma unroll
    for (int qq = 0; qq < 4; ++qq) {
        f16x8 hv;
        #pragma unroll
        for (int j = 0; j < 8; ++j) {
            int e = qq * 8 + j;
            float num = 0.0f;
            #pragma unroll
            for (int d2 = 0; d2 < 32; ++d2) num += q[d2] * kvb[d2 * 32 + e];
            hv[j] = (f16)(num * rden);
        }
        *reinterpret_cast<f16x8*>(ATh + ob + qq * 8) = hv;
    }
}

// ---------------------------------------------------------------------------
// K5: BN batch stats per channel (biased var), fp64 accumulation.
// ---------------------------------------------------------------------------
__global__ __launch_bounds__(1024) void bn_stats(
    const float* __restrict__ out2, float* __restrict__ stats)
{
    int o = blockIdx.x, t = threadIdx.x;
    double s = 0.0, ss = 0.0;
    for (int b = 0; b < B_; ++b) {
        const float* p = out2 + ((size_t)b * C_ + o) * N_;
        float4 v = *reinterpret_cast<const float4*>(&p[t * 4]);
        s  += (double)v.x + (double)v.y + (double)v.z + (double)v.w;
        ss += (double)v.x * v.x + (double)v.y * v.y + (double)v.z * v.z + (double)v.w * v.w;
    }
    __shared__ double rs[1024], rss[1024];
    rs[t] = s; rss[t] = ss;
    __syncthreads();
    for (int st = 512; st > 0; st >>= 1) {
        if (t < st) { rs[t] += rs[t + st]; rss[t] += rss[t + st]; }
        __syncthreads();
    }
    if (t == 0) {
        double mean = rs[0] / 32768.0;
        double var  = rss[0] / 32768.0 - mean * mean;
        stats[o * 2 + 0] = (float)mean;
        stats[o * 2 + 1] = (float)(1.0 / sqrt(var + 1e-5));
    }
}

// K6: in-place BN apply
__global__ __launch_bounds__(256) void bn_apply(
    float* __restrict__ out, const float* __restrict__ stats,
    const float* __restrict__ gamma, const float* __restrict__ beta)
{
    size_t i = ((size_t)blockIdx.x * 256 + threadIdx.x) * 4;
    int o = (int)((i >> 12) & 255);
    float m = stats[o * 2], r = stats[o * 2 + 1];
    float g = gamma[o] * r;
    float c = beta[o] - m * g;
    float4 v = *reinterpret_cast<float4*>(&out[i]);
    v.x = v.x * g + c; v.y = v.y * g + c;
    v.z = v.z * g + c; v.w = v.w * g + c;
    *reinterpret_cast<float4*>(&out[i]) = v;
}

// ---------------------------------------------------------------------------
extern "C" void kernel_launch(void* const* d_in, const int* in_sizes, int n_in,
                              void* d_out, int out_size, void* d_ws, size_t ws_size,
                              hipStream_t stream)
{
    (void)in_sizes; (void)n_in; (void)out_size; (void)ws_size;

    const float* x     = (const float*)d_in[0];
    const float* qmem  = (const float*)d_in[1];
    const float* kmem  = (const float*)d_in[2];
    const float* vmem  = (const float*)d_in[3];
    const float* Wq    = (const float*)d_in[4];
    const float* Wk    = (const float*)d_in[5];
    const float* Wv    = (const float*)d_in[6];
    const float* Wo    = (const float*)d_in[7];
    const float* gamma = (const float*)d_in[8];
    const float* beta  = (const float*)d_in[9];

    const size_t TSZ = (size_t)B_ * C_ * N_;     // 8,388,608
    float* out0 = (float*)d_out;
    float* outq = out0 + TSZ;
    float* outk = outq + TSZ;
    float* outv = outk + TSZ;

    char* w = (char*)d_ws;
    f16* XTh = (f16*)w;           w += TSZ * 2;
    f16* XTl = (f16*)w;           w += TSZ * 2;
    f16* ATh = (f16*)w;           w += TSZ * 2;
    f16* Wch = (f16*)w;           w += 1024 * 256 * 2;
    f16* Wcl = (f16*)w;           w += 1024 * 256 * 2;
    int* pkv = (int*)w;           w += 64 * 8 * 1024 * 4;
    int* pck = (int*)w;           w += 64 * 8 * 32 * 4;
    int* pcv = (int*)w;           w += 64 * 8 * 32 * 4;
    float* kvp   = (float*)w;     w += 64 * 1024 * 4;
    float* ksump = (float*)w;     w += 64 * 32 * 4;
    float* stats = (float*)w;     w += 256 * 2 * 4;

    dim3 blk(256);

    // K0: transpose/split X, split weights
    transpose_split<<<dim3(16, 8, 8), blk, 0, stream>>>(x, XTh, XTl);
    weight_split<<<dim3(256), blk, 0, stream>>>(Wq, Wk, Wv, Wo, Wch, Wcl);

    // K1: QKV GEMM (split fp16, A-direct, B-only dbuf LDS) + LIF
    mfma_gemm<true, true><<<dim3(1536), blk, 0, stream>>>(
        Wch, Wcl, XTh, XTl, qmem, kmem, vmem, outq, outk, outv);

    // K2: exact kv/ksum via two-stage popcount
    kv_stage1<<<dim3(64, 8), blk, 0, stream>>>(outk, outv, pkv, pck, pcv);
    kv_stage2<<<dim3(64), blk, 0, stream>>>(pkv, pck, pcv, kvp, ksump);

    // K3: attention -> fp16 ATh [b][n][c]
    att_kernel<<<dim3(16, 64), blk, 0, stream>>>(outq, kvp, ksump, ATh);

    // K4: Wo GEMM (single-plane fp16) -> out0
    mfma_gemm<false, false><<<dim3(512), blk, 0, stream>>>(
        Wch, Wcl, ATh, ATh, nullptr, nullptr, nullptr, out0, nullptr, nullptr);

    // K5/K6: BatchNorm
    bn_stats<<<dim3(256), dim3(1024), 0, stream>>>(out0, stats);
    bn_apply<<<dim3(8192), blk, 0, stream>>>(out0, stats, gamma, beta);
}

// Round 9
// 184.815 us; speedup vs baseline: 1.0363x; 1.0363x over previous
//
#include <hip/hip_runtime.h>

#define B_ 8
#define C_ 256
#define N_ 4096
#define HD_ 32

#define ALPHA_ 0.36787944117144233f   // elu(-1)+1 = e^-1
#define BETAS_ (2.0f - ALPHA_)        // spike value 2.0 = ALPHA_ + BETAS_
#define SCALE_ 0.17677669529663687f   // 32^-0.5

typedef _Float16 f16;
typedef _Float16 f16x8 __attribute__((ext_vector_type(8)));
typedef float f32x4 __attribute__((ext_vector_type(4)));
typedef unsigned long long u64;
typedef __attribute__((address_space(3))) f16 lds_f16;

#define MFMA(a,b,c) __builtin_amdgcn_mfma_f32_16x16x32_f16((a),(b),(c),0,0,0)

#define GLDS(g, l) __builtin_amdgcn_global_load_lds( \
    (const __attribute__((address_space(1))) void*)(g), \
    (__attribute__((address_space(3))) void*)(l), 16, 0, 0)

#define DSR(dst, off) asm volatile("ds_read_b128 %0, %1" : "=v"(dst) : "v"(off))

template<int N> __device__ __forceinline__ void wait_vmcnt() {
    if constexpr (N == 0)       asm volatile("s_waitcnt vmcnt(0)" ::: "memory");
    else if constexpr (N == 2)  asm volatile("s_waitcnt vmcnt(2)" ::: "memory");
    else if constexpr (N == 4)  asm volatile("s_waitcnt vmcnt(4)" ::: "memory");
    else if constexpr (N == 8)  asm volatile("s_waitcnt vmcnt(8)" ::: "memory");
    else if constexpr (N == 16) asm volatile("s_waitcnt vmcnt(16)" ::: "memory");
}

// ---------------------------------------------------------------------------
// K0a: transpose + split X: x[b][i][n] f32 -> XTh/XTl[b][n][i] f16
// ---------------------------------------------------------------------------
__global__ __launch_bounds__(256) void transpose_split(
    const float* __restrict__ x, f16* __restrict__ XTh, f16* __restrict__ XTl)
{
    __shared__ float tile[32][257];
    int t = threadIdx.x;
    int b = blockIdx.z, i0 = blockIdx.y * 32, n0 = blockIdx.x * 256;
    const float* src = x + ((size_t)b * C_ + i0) * N_ + n0;
    int r = t >> 3, c0 = (t & 7) * 32;
    #pragma unroll
    for (int q = 0; q < 8; ++q) {
        float4 v = *reinterpret_cast<const float4*>(src + (size_t)r * N_ + c0 + q * 4);
        tile[r][c0 + q*4 + 0] = v.x; tile[r][c0 + q*4 + 1] = v.y;
        tile[r][c0 + q*4 + 2] = v.z; tile[r][c0 + q*4 + 3] = v.w;
    }
    __syncthreads();
    size_t ob = ((size_t)b * N_ + n0 + t) * C_ + i0;
    #pragma unroll
    for (int q = 0; q < 4; ++q) {
        f16x8 hv, lv;
        #pragma unroll
        for (int j = 0; j < 8; ++j) {
            float v = tile[q*8 + j][t];
            f16 h = (f16)v;
            hv[j] = h;
            lv[j] = (f16)(v - (float)h);
        }
        *reinterpret_cast<f16x8*>(XTh + ob + q*8) = hv;
        *reinterpret_cast<f16x8*>(XTl + ob + q*8) = lv;
    }
}

// ---------------------------------------------------------------------------
// K0b: split weights into Wc[1024][256]
// ---------------------------------------------------------------------------
__global__ __launch_bounds__(256) void weight_split(
    const float* __restrict__ Wq, const float* __restrict__ Wk,
    const float* __restrict__ Wv, const float* __restrict__ Wo,
    f16* __restrict__ Wch, f16* __restrict__ Wcl)
{
    int idx4 = (blockIdx.x * 256 + threadIdx.x) * 4;
    int o = idx4 >> 8, i = idx4 & 255;
    const float* src = (o < 256) ? (Wq + (size_t)o * 256)
                     : (o < 512) ? (Wk + (size_t)(o - 256) * 256)
                     : (o < 768) ? (Wv + (size_t)(o - 512) * 256)
                                 : (Wo + (size_t)(o - 768) * 256);
    float4 v = *reinterpret_cast<const float4*>(src + i);
    f16 h0 = (f16)v.x, h1 = (f16)v.y, h2 = (f16)v.z, h3 = (f16)v.w;
    f16 hh[4] = { h0, h1, h2, h3 };
    f16 ll[4] = { (f16)(v.x - (float)h0), (f16)(v.y - (float)h1),
                  (f16)(v.z - (float)h2), (f16)(v.w - (float)h3) };
    *reinterpret_cast<uint2*>(Wch + idx4) = *reinterpret_cast<uint2*>(hh);
    *reinterpret_cast<uint2*>(Wcl + idx4) = *reinterpret_cast<uint2*>(ll);
}

// ---------------------------------------------------------------------------
// MFMA GEMM, 3-deep counted-vmcnt pipeline (T4).
// Tile 128o x 128n, K-step 32, 4 waves (2m x 2n), wave tile 64x64.
// A (weights) direct from global (L2-hot).  B in LDS, 3 buffers, staged 2
// tiles ahead via global_load_lds; per step ONE counted wait vmcnt(NGL)
// drains {s(t+1), A(t)} and leaves s(t+2) in flight across MFMA+barrier.
// RACE FIX (R9): prologue drains s(0) per-wave (vmcnt(NGL)) AND barriers
// before the first ds_read — vmcnt is per-wave; without the barrier, a wave
// could read LDS slots whose data comes from another wave's in-flight stage.
// LIF epilogue additionally ballots spike bits into per-channel row masks.
// ---------------------------------------------------------------------------
template<bool LIF, bool FULLP>
__global__ __launch_bounds__(256, 3) void mfma_gemm(
    const f16* __restrict__ Wch, const f16* __restrict__ Wcl,
    const f16* __restrict__ Bh,  const f16* __restrict__ Bl,
    const float* __restrict__ mq, const float* __restrict__ mk2,
    const float* __restrict__ mv,
    float* __restrict__ o0, float* __restrict__ o1, float* __restrict__ o2,
    u64* __restrict__ rowAll)
{
    constexpr int SLOTS = FULLP ? 1024 : 512;   // 16B slots per buffer
    constexpr int NGL   = FULLP ? 4 : 2;        // gload_lds per thread per step

    int gid = blockIdx.x;
    int b = gid & 7, slot = gid >> 3;           // batch -> XCD
    int conv, oTi, nt;
    if (LIF) { conv = slot % 3; int rest = slot / 3; oTi = rest & 1; nt = rest >> 1; }
    else     { conv = 0;        oTi = slot & 1;      nt = slot >> 1; }
    int wRow0 = (LIF ? conv * 256 : 768) + oTi * 128;
    int chOut0 = oTi * 128;
    int nT = nt * 128;

    const float* memP = nullptr; float* outP; u64* rowP = nullptr;
    if (LIF) {
        memP = (conv == 0) ? mq : (conv == 1) ? mk2 : mv;
        outP = (conv == 0) ? o0 : (conv == 1) ? o1 : o2;
        rowP = rowAll + (size_t)conv * (8 * 256 * 64);
    } else outP = o0;

    __shared__ __align__(16) f16 smem[3][SLOTS * 8];

    int t = threadIdx.x;
    int wid = t >> 6, lane = t & 63;
    int wm = wid >> 1, wn = wid & 1;
    int lr = lane & 15, g = lane >> 4;

    // B staging global pointers (k=0), chunk-XOR pre-swizzled source
    const f16* gB[NGL];
    #pragma unroll
    for (int i = 0; i < NGL; ++i) {
        int s = i * 256 + t;
        int sp = s & 511;
        int r = sp >> 2, c = (sp & 3) ^ ((r >> 1) & 3);
        const f16* plane = (s < 512) ? Bh : Bl;
        gB[i] = plane + ((size_t)b * N_ + nT + r) * 256 + c * 8;
    }

    // A fragment offsets (direct-global)
    int aOff[4];
    #pragma unroll
    for (int m = 0; m < 4; ++m)
        aOff[m] = (wRow0 + wm * 64 + m * 16 + lr) * 256 + g * 8;

    // B fragment LDS byte offsets (same XOR involution)
    unsigned lbase = (unsigned)(size_t)(lds_f16*)&smem[0][0];
    unsigned offB[4];
    #pragma unroll
    for (int n = 0; n < 4; ++n) {
        int r = wn * 64 + n * 16 + lr;
        offB[n] = (unsigned)((r * 4 + (g ^ ((r >> 1) & 3))) * 16);
    }

    f32x4 acc[4][4];
    #pragma unroll
    for (int m = 0; m < 4; ++m)
        #pragma unroll
        for (int n = 0; n < 4; ++n) acc[m][n] = (f32x4){0.f, 0.f, 0.f, 0.f};

    // prologue: stage tiles 0 and 1; drain s(0) (keep s(1) in flight) and
    // BARRIER so every wave's s(0) LDS writes are visible before any ds_read.
    #pragma unroll
    for (int i = 0; i < NGL; ++i) GLDS(gB[i],      &smem[0][(i * 256 + t) * 8]);
    #pragma unroll
    for (int i = 0; i < NGL; ++i) GLDS(gB[i] + 32, &smem[1][(i * 256 + t) * 8]);
    wait_vmcnt<NGL>();
    __builtin_amdgcn_s_barrier();
    __builtin_amdgcn_sched_barrier(0);

#define GEMM_STEP(KS) do { \
    constexpr int ks = (KS); \
    f16x8 ah[4], al[4]; \
    _Pragma("unroll") \
    for (int m = 0; m < 4; ++m) { \
        ah[m] = *reinterpret_cast<const f16x8*>(Wch + aOff[m] + ks * 32); \
        if (FULLP) al[m] = *reinterpret_cast<const f16x8*>(Wcl + aOff[m] + ks * 32); \
    } \
    __builtin_amdgcn_sched_barrier(0); \
    if constexpr (ks < 6) { \
        _Pragma("unroll") \
        for (int i = 0; i < NGL; ++i) \
            GLDS(gB[i] + (ks + 2) * 32, &smem[(ks + 2) % 3][(i * 256 + t) * 8]); \
    } \
    __builtin_amdgcn_sched_barrier(0); \
    const unsigned base = lbase + (unsigned)((ks % 3) * (SLOTS * 16)); \
    f16x8 bhf[4], blf[4]; \
    _Pragma("unroll") \
    for (int n = 0; n < 4; ++n) { \
        DSR(bhf[n], base + offB[n]); \
        if (FULLP) DSR(blf[n], base + offB[n] + 8192); \
    } \
    asm volatile("s_waitcnt lgkmcnt(0)" ::: "memory"); \
    __builtin_amdgcn_sched_barrier(0); \
    wait_vmcnt<(ks < 6) ? (FULLP ? 4 : 2) : 0>();  /* drain s(ks+1)+A(ks), keep s(ks+2) */ \
    __builtin_amdgcn_sched_barrier(0); \
    _Pragma("unroll") \
    for (int n = 0; n < 4; ++n) \
        _Pragma("unroll") \
        for (int m = 0; m < 4; ++m) { \
            acc[m][n] = MFMA(ah[m], bhf[n], acc[m][n]); \
            if (FULLP) { \
                acc[m][n] = MFMA(ah[m], blf[n], acc[m][n]); \
                acc[m][n] = MFMA(al[m], bhf[n], acc[m][n]); \
            } \
        } \
    __builtin_amdgcn_sched_barrier(0); \
    __builtin_amdgcn_s_barrier(); \
    __builtin_amdgcn_sched_barrier(0); \
} while (0)

    GEMM_STEP(0); GEMM_STEP(1); GEMM_STEP(2); GEMM_STEP(3);
    GEMM_STEP(4); GEMM_STEP(5); GEMM_STEP(6); GEMM_STEP(7);
#undef GEMM_STEP

    // epilogue: D layout col = lane&15 (n), row = (lane>>4)*4 + reg (o)
    if (LIF) {
        #pragma unroll
        for (int m = 0; m < 4; ++m) {
            int oLoc = chOut0 + wm * 64 + m * 16 + g * 4;
            u64 rw0 = 0, rw1 = 0, rw2 = 0, rw3 = 0;
            #pragma unroll
            for (int n = 0; n < 4; ++n) {
                int nn = nT + wn * 64 + n * 16 + lr;
                #pragma unroll
                for (int r = 0; r < 4; ++r) {
                    size_t idx = ((size_t)b * C_ + oLoc + r) * N_ + nn;
                    float mm = memP[idx];
                    float v = 0.5f * mm + acc[m][n][r] - (mm > 1.0f ? 1.0f : 0.0f);
                    outP[idx] = v;
                    u64 bl = __ballot(v > 1.0f);
                    u64 fld = ((bl >> (g * 16)) & 0xFFFFull) << (n * 16);
                    if (r == 0) rw0 |= fld; else if (r == 1) rw1 |= fld;
                    else if (r == 2) rw2 |= fld; else rw3 |= fld;
                }
            }
            if (lr == 0) {
                size_t rb = ((size_t)b * 256 + oLoc) * 64 + (nt * 2 + wn);
                rowP[rb]       = rw0;
                rowP[rb + 64]  = rw1;
                rowP[rb + 128] = rw2;
                rowP[rb + 192] = rw3;
            }
        }
    } else {
        #pragma unroll
        for (int m = 0; m < 4; ++m) {
            int oLoc = chOut0 + wm * 64 + m * 16 + g * 4;
            #pragma unroll
            for (int n = 0; n < 4; ++n) {
                int nn = nT + wn * 64 + n * 16 + lr;
                #pragma unroll
                for (int r = 0; r < 4; ++r) {
                    size_t idx = ((size_t)b * C_ + oLoc + r) * N_ + nn;
                    outP[idx] = acc[m][n][r];
                }
            }
        }
    }
}

// ---------------------------------------------------------------------------
// K2 stage 1: per (bh, 8-word n-slice): partial popcounts from row masks.
// ---------------------------------------------------------------------------
__global__ __launch_bounds__(256) void kv_stage1(
    const u64* __restrict__ krow, const u64* __restrict__ vrow,
    int* __restrict__ pkv, int* __restrict__ pck, int* __restrict__ pcv)
{
    int bh = blockIdx.x, sl = blockIdx.y;
    int b = bh >> 3, h = bh & 7;
    __shared__ u64 kr[32][9], vr[32][9];
    int t = threadIdx.x;
    {
        int d = t >> 3, w = t & 7;
        size_t a = ((size_t)b * 256 + h * HD_ + d) * 64 + sl * 8 + w;
        kr[d][w] = krow[a];
        vr[d][w] = vrow[a];
    }
    __syncthreads();

    int base = bh * 8 + sl;
    if (t < 32) {
        int c = 0;
        #pragma unroll
        for (int w = 0; w < 8; ++w) c += __popcll(kr[t][w]);
        pck[base * 32 + t] = c;
    } else if (t < 64) {
        int dd = t - 32, c = 0;
        #pragma unroll
        for (int w = 0; w < 8; ++w) c += __popcll(vr[dd][w]);
        pcv[base * 32 + dd] = c;
    }
    int d = t >> 3, e0 = (t & 7) * 4;
    #pragma unroll
    for (int j = 0; j < 4; ++j) {
        int e = e0 + j, P = 0;
        #pragma unroll
        for (int w = 0; w < 8; ++w) P += __popcll(kr[d][w] & vr[e][w]);
        pkv[(size_t)base * 1024 + d * 32 + e] = P;
    }
}

// K2 stage 2: reduce 8 slices -> kvp, ksump
__global__ __launch_bounds__(256) void kv_stage2(
    const int* __restrict__ pkv, const int* __restrict__ pck,
    const int* __restrict__ pcv, float* __restrict__ kvp, float* __restrict__ ksump)
{
    int bh = blockIdx.x, t = threadIdx.x;
    __shared__ float ck[32], cv[32];
    if (t < 32) {
        int s = 0;
        #pragma unroll
        for (int sl = 0; sl < 8; ++sl) s += pck[(bh * 8 + sl) * 32 + t];
        ck[t] = (float)s;
    } else if (t < 64) {
        int dd = t - 32, s = 0;
        #pragma unroll
        for (int sl = 0; sl < 8; ++sl) s += pcv[(bh * 8 + sl) * 32 + dd];
        cv[dd] = (float)s;
    }
    __syncthreads();
    int d = t >> 3, e0 = (t & 7) * 4;
    #pragma unroll
    for (int j = 0; j < 4; ++j) {
        int e = e0 + j, P = 0;
        #pragma unroll
        for (int sl = 0; sl < 8; ++sl) P += pkv[(size_t)(bh * 8 + sl) * 1024 + d * 32 + e];
        float skv = 2.0f * (float)P - ck[d];
        float sv  = 2.0f * cv[e] - 4096.0f;
        kvp[(size_t)bh * 1024 + d * 32 + e] = ALPHA_ * sv + BETAS_ * skv;
    }
    if ((t & 7) == 0)
        ksump[bh * 32 + d] = ALPHA_ * 4096.0f + BETAS_ * ck[d];
}

// ---------------------------------------------------------------------------
// K3: att = SCALE*(q.kv)/(q.ksum+1e-6); q from row mask; out fp16 ATh [b][n][c]
// ---------------------------------------------------------------------------
__global__ __launch_bounds__(256) void att_kernel(
    const u64* __restrict__ qrow, const float* __restrict__ kvp,
    const float* __restrict__ ksump, f16* __restrict__ ATh)
{
    int bh = blockIdx.y; int b = bh >> 3, h = bh & 7;
    int n0 = blockIdx.x * 256;

    __shared__ u64 qw[32][5];
    int t = threadIdx.x;
    if (t < 128) {
        int d2 = t >> 2, w4 = t & 3;
        qw[d2][w4] = qrow[((size_t)b * 256 + h * HD_ + d2) * 64 + (n0 >> 6) + w4];
    }
    __syncthreads();

    float q[32];
    #pragma unroll
    for (int d2 = 0; d2 < 32; ++d2)
        q[d2] = ((qw[d2][t >> 6] >> (t & 63)) & 1) ? 2.0f : ALPHA_;

    const float* ksb = ksump + bh * 32;
    float den = 1e-6f;
    #pragma unroll
    for (int d2 = 0; d2 < 32; ++d2) den += q[d2] * ksb[d2];
    float rden = SCALE_ / den;

    const float* kvb = kvp + (size_t)bh * 1024;
    size_t ob = ((size_t)b * N_ + n0 + t) * C_ + h * HD_;
    #pragma unroll
    for (int qq = 0; qq < 4; ++qq) {
        f16x8 hv;
        #pragma unroll
        for (int j = 0; j < 8; ++j) {
            int e = qq * 8 + j;
            float num = 0.0f;
            #pragma unroll
            for (int d2 = 0; d2 < 32; ++d2) num += q[d2] * kvb[d2 * 32 + e];
            hv[j] = (f16)(num * rden);
        }
        *reinterpret_cast<f16x8*>(ATh + ob + qq * 8) = hv;
    }
}

// ---------------------------------------------------------------------------
// K5: BN batch stats per channel (biased var), fp64 accumulation.
// ---------------------------------------------------------------------------
__global__ __launch_bounds__(1024) void bn_stats(
    const float* __restrict__ out2, float* __restrict__ stats)
{
    int o = blockIdx.x, t = threadIdx.x;
    double s = 0.0, ss = 0.0;
    for (int b = 0; b < B_; ++b) {
        const float* p = out2 + ((size_t)b * C_ + o) * N_;
        float4 v = *reinterpret_cast<const float4*>(&p[t * 4]);
        s  += (double)v.x + (double)v.y + (double)v.z + (double)v.w;
        ss += (double)v.x * v.x + (double)v.y * v.y + (double)v.z * v.z + (double)v.w * v.w;
    }
    __shared__ double rs[1024], rss[1024];
    rs[t] = s; rss[t] = ss;
    __syncthreads();
    for (int st = 512; st > 0; st >>= 1) {
        if (t < st) { rs[t] += rs[t + st]; rss[t] += rss[t + st]; }
        __syncthreads();
    }
    if (t == 0) {
        double mean = rs[0] / 32768.0;
        double var  = rss[0] / 32768.0 - mean * mean;
        stats[o * 2 + 0] = (float)mean;
        stats[o * 2 + 1] = (float)(1.0 / sqrt(var + 1e-5));
    }
}

// K6: in-place BN apply
__global__ __launch_bounds__(256) void bn_apply(
    float* __restrict__ out, const float* __restrict__ stats,
    const float* __restrict__ gamma, const float* __restrict__ beta)
{
    size_t i = ((size_t)blockIdx.x * 256 + threadIdx.x) * 4;
    int o = (int)((i >> 12) & 255);
    float m = stats[o * 2], r = stats[o * 2 + 1];
    float g = gamma[o] * r;
    float c = beta[o] - m * g;
    float4 v = *reinterpret_cast<float4*>(&out[i]);
    v.x = v.x * g + c; v.y = v.y * g + c;
    v.z = v.z * g + c; v.w = v.w * g + c;
    *reinterpret_cast<float4*>(&out[i]) = v;
}

// ---------------------------------------------------------------------------
extern "C" void kernel_launch(void* const* d_in, const int* in_sizes, int n_in,
                              void* d_out, int out_size, void* d_ws, size_t ws_size,
                              hipStream_t stream)
{
    (void)in_sizes; (void)n_in; (void)out_size; (void)ws_size;

    const float* x     = (const float*)d_in[0];
    const float* qmem  = (const float*)d_in[1];
    const float* kmem  = (const float*)d_in[2];
    const float* vmem  = (const float*)d_in[3];
    const float* Wq    = (const float*)d_in[4];
    const float* Wk    = (const float*)d_in[5];
    const float* Wv    = (const float*)d_in[6];
    const float* Wo    = (const float*)d_in[7];
    const float* gamma = (const float*)d_in[8];
    const float* beta  = (const float*)d_in[9];

    const size_t TSZ = (size_t)B_ * C_ * N_;     // 8,388,608
    float* out0 = (float*)d_out;
    float* outq = out0 + TSZ;
    float* outk = outq + TSZ;
    float* outv = outk + TSZ;

    const size_t RSZ = (size_t)8 * 256 * 64;     // row-mask words per tensor
    char* w = (char*)d_ws;
    f16* XTh = (f16*)w;           w += TSZ * 2;
    f16* XTl = (f16*)w;           w += TSZ * 2;
    f16* ATh = (f16*)w;           w += TSZ * 2;
    f16* Wch = (f16*)w;           w += 1024 * 256 * 2;
    f16* Wcl = (f16*)w;           w += 1024 * 256 * 2;
    u64* rowm = (u64*)w;          w += 3 * RSZ * 8;
    int* pkv = (int*)w;           w += 64 * 8 * 1024 * 4;
    int* pck = (int*)w;           w += 64 * 8 * 32 * 4;
    int* pcv = (int*)w;           w += 64 * 8 * 32 * 4;
    float* kvp   = (float*)w;     w += 64 * 1024 * 4;
    float* ksump = (float*)w;     w += 64 * 32 * 4;
    float* stats = (float*)w;     w += 256 * 2 * 4;

    dim3 blk(256);

    // K0: transpose/split X, split weights
    transpose_split<<<dim3(16, 8, 8), blk, 0, stream>>>(x, XTh, XTl);
    weight_split<<<dim3(256), blk, 0, stream>>>(Wq, Wk, Wv, Wo, Wch, Wcl);

    // K1: QKV GEMM (split fp16, counted 3-deep pipeline) + LIF + spike masks
    mfma_gemm<true, true><<<dim3(1536), blk, 0, stream>>>(
        Wch, Wcl, XTh, XTl, qmem, kmem, vmem, outq, outk, outv, rowm);

    // K2: exact kv/ksum from row masks (2 MB instead of 128 MB)
    kv_stage1<<<dim3(64, 8), blk, 0, stream>>>(rowm + RSZ, rowm + 2 * RSZ, pkv, pck, pcv);
    kv_stage2<<<dim3(64), blk, 0, stream>>>(pkv, pck, pcv, kvp, ksump);

    // K3: attention from q mask -> fp16 ATh [b][n][c]
    att_kernel<<<dim3(16, 64), blk, 0, stream>>>(rowm, kvp, ksump, ATh);

    // K4: Wo GEMM (single-plane fp16) -> out0
    mfma_gemm<false, false><<<dim3(512), blk, 0, stream>>>(
        Wch, Wcl, ATh, ATh, nullptr, nullptr, nullptr, out0, nullptr, nullptr, nullptr);

    // K5/K6: BatchNorm
    bn_stats<<<dim3(256), dim3(1024), 0, stream>>>(out0, stats);
    bn_apply<<<dim3(8192), blk, 0, stream>>>(out0, stats, gamma, beta);
}

// Round 10
// 174.580 us; speedup vs baseline: 1.0970x; 1.0586x over previous
//
#include <hip/hip_runtime.h>

#define B_ 8
#define C_ 256
#define N_ 4096
#define HD_ 32

#define ALPHA_ 0.36787944117144233f   // elu(-1)+1 = e^-1
#define BETAS_ (2.0f - ALPHA_)        // spike value 2.0 = ALPHA_ + BETAS_
#define SCALE_ 0.17677669529663687f   // 32^-0.5

typedef _Float16 f16;
typedef _Float16 f16x8 __attribute__((ext_vector_type(8)));
typedef float f32x4 __attribute__((ext_vector_type(4)));
typedef unsigned long long u64;
typedef __attribute__((address_space(3))) f16 lds_f16;

#define MFMA(a,b,c) __builtin_amdgcn_mfma_f32_16x16x32_f16((a),(b),(c),0,0,0)

#define GLDS(g, l) __builtin_amdgcn_global_load_lds( \
    (const __attribute__((address_space(1))) void*)(g), \
    (__attribute__((address_space(3))) void*)(l), 16, 0, 0)

#define DSR(dst, off) asm volatile("ds_read_b128 %0, %1" : "=v"(dst) : "v"(off))

// A-fragment prefetch: plain global 16B load with compile-time byte offset.
#define GLA(dst, ptr, ofs) asm volatile( \
    "global_load_dwordx4 %0, %1, off offset:%c2" \
    : "=v"(dst) : "v"(ptr), "i"(ofs))

template<int N> __device__ __forceinline__ void wait_vmcnt() {
    if constexpr (N == 0)       asm volatile("s_waitcnt vmcnt(0)" ::: "memory");
    else if constexpr (N == 2)  asm volatile("s_waitcnt vmcnt(2)" ::: "memory");
    else if constexpr (N == 4)  asm volatile("s_waitcnt vmcnt(4)" ::: "memory");
    else if constexpr (N == 6)  asm volatile("s_waitcnt vmcnt(6)" ::: "memory");
    else if constexpr (N == 8)  asm volatile("s_waitcnt vmcnt(8)" ::: "memory");
    else if constexpr (N == 12) asm volatile("s_waitcnt vmcnt(12)" ::: "memory");
    else if constexpr (N == 16) asm volatile("s_waitcnt vmcnt(16)" ::: "memory");
}

// ---------------------------------------------------------------------------
// K0a: transpose + split X: x[b][i][n] f32 -> XTh/XTl[b][n][i] f16
// ---------------------------------------------------------------------------
__global__ __launch_bounds__(256) void transpose_split(
    const float* __restrict__ x, f16* __restrict__ XTh, f16* __restrict__ XTl)
{
    __shared__ float tile[32][257];
    int t = threadIdx.x;
    int b = blockIdx.z, i0 = blockIdx.y * 32, n0 = blockIdx.x * 256;
    const float* src = x + ((size_t)b * C_ + i0) * N_ + n0;
    int r = t >> 3, c0 = (t & 7) * 32;
    #pragma unroll
    for (int q = 0; q < 8; ++q) {
        float4 v = *reinterpret_cast<const float4*>(src + (size_t)r * N_ + c0 + q * 4);
        tile[r][c0 + q*4 + 0] = v.x; tile[r][c0 + q*4 + 1] = v.y;
        tile[r][c0 + q*4 + 2] = v.z; tile[r][c0 + q*4 + 3] = v.w;
    }
    __syncthreads();
    size_t ob = ((size_t)b * N_ + n0 + t) * C_ + i0;
    #pragma unroll
    for (int q = 0; q < 4; ++q) {
        f16x8 hv, lv;
        #pragma unroll
        for (int j = 0; j < 8; ++j) {
            float v = tile[q*8 + j][t];
            f16 h = (f16)v;
            hv[j] = h;
            lv[j] = (f16)(v - (float)h);
        }
        *reinterpret_cast<f16x8*>(XTh + ob + q*8) = hv;
        *reinterpret_cast<f16x8*>(XTl + ob + q*8) = lv;
    }
}

// ---------------------------------------------------------------------------
// K0b: split weights into Wc[1024][256]
// ---------------------------------------------------------------------------
__global__ __launch_bounds__(256) void weight_split(
    const float* __restrict__ Wq, const float* __restrict__ Wk,
    const float* __restrict__ Wv, const float* __restrict__ Wo,
    f16* __restrict__ Wch, f16* __restrict__ Wcl)
{
    int idx4 = (blockIdx.x * 256 + threadIdx.x) * 4;
    int o = idx4 >> 8, i = idx4 & 255;
    const float* src = (o < 256) ? (Wq + (size_t)o * 256)
                     : (o < 512) ? (Wk + (size_t)(o - 256) * 256)
                     : (o < 768) ? (Wv + (size_t)(o - 512) * 256)
                                 : (Wo + (size_t)(o - 768) * 256);
    float4 v = *reinterpret_cast<const float4*>(src + i);
    f16 h0 = (f16)v.x, h1 = (f16)v.y, h2 = (f16)v.z, h3 = (f16)v.w;
    f16 hh[4] = { h0, h1, h2, h3 };
    f16 ll[4] = { (f16)(v.x - (float)h0), (f16)(v.y - (float)h1),
                  (f16)(v.z - (float)h2), (f16)(v.w - (float)h3) };
    *reinterpret_cast<uint2*>(Wch + idx4) = *reinterpret_cast<uint2*>(hh);
    *reinterpret_cast<uint2*>(Wcl + idx4) = *reinterpret_cast<uint2*>(ll);
}

// ---------------------------------------------------------------------------
// MFMA GEMM, fully pipelined: A (weights) prefetched one step ahead into
// double-buffered registers (asm global_load_dwordx4, FIFO-exact); B staged
// 2 steps ahead in 3 LDS buffers (global_load_lds).  Per step TWO counted
// waits: pre-MFMA drains A(t) (issued a full step earlier, latency hidden
// under step t-1's MFMA); post-MFMA drains s(t+1) (issued ~2 steps earlier),
// leaving {A(t+1), s(t+2)} in flight across the barrier.  NEVER vmcnt(0)
// in the steady state.
// Tile 128o x 128n, K-step 32, 4 waves (2m x 2n), wave tile 64x64.
// RACE-safe: prologue drains s(0)+A(0) then barriers (R9 fix kept).
// LIF epilogue ballots spike bits into per-channel row masks.
// ---------------------------------------------------------------------------
template<bool LIF, bool FULLP>
__global__ __launch_bounds__(256, 2) void mfma_gemm(
    const f16* __restrict__ Wch, const f16* __restrict__ Wcl,
    const f16* __restrict__ Bh,  const f16* __restrict__ Bl,
    const float* __restrict__ mq, const float* __restrict__ mk2,
    const float* __restrict__ mv,
    float* __restrict__ o0, float* __restrict__ o1, float* __restrict__ o2,
    u64* __restrict__ rowAll)
{
    constexpr int SLOTS = FULLP ? 1024 : 512;   // 16B slots per buffer
    constexpr int NGL   = FULLP ? 4 : 2;        // gload_lds per thread per step
    constexpr int NA    = FULLP ? 8 : 4;        // A reg-loads per thread per step

    int gid = blockIdx.x;
    int b = gid & 7, slot = gid >> 3;           // batch -> XCD
    int conv, oTi, nt;
    if (LIF) { conv = slot % 3; int rest = slot / 3; oTi = rest & 1; nt = rest >> 1; }
    else     { conv = 0;        oTi = slot & 1;      nt = slot >> 1; }
    int wRow0 = (LIF ? conv * 256 : 768) + oTi * 128;
    int chOut0 = oTi * 128;
    int nT = nt * 128;

    const float* memP = nullptr; float* outP; u64* rowP = nullptr;
    if (LIF) {
        memP = (conv == 0) ? mq : (conv == 1) ? mk2 : mv;
        outP = (conv == 0) ? o0 : (conv == 1) ? o1 : o2;
        rowP = rowAll + (size_t)conv * (8 * 256 * 64);
    } else outP = o0;

    __shared__ __align__(16) f16 smem[3][SLOTS * 8];

    int t = threadIdx.x;
    int wid = t >> 6, lane = t & 63;
    int wm = wid >> 1, wn = wid & 1;
    int lr = lane & 15, g = lane >> 4;

    // B staging global pointers (k=0), chunk-XOR pre-swizzled source
    const f16* gB[NGL];
    #pragma unroll
    for (int i = 0; i < NGL; ++i) {
        int s = i * 256 + t;
        int sp = s & 511;
        int r = sp >> 2, c = (sp & 3) ^ ((r >> 1) & 3);
        const f16* plane = (s < 512) ? Bh : Bl;
        gB[i] = plane + ((size_t)b * N_ + nT + r) * 256 + c * 8;
    }

    // A fragment base pointers (k=0); per-step k advance via offset immediate
    const f16* aPh[4]; const f16* aPl[4];
    #pragma unroll
    for (int m = 0; m < 4; ++m) {
        int off = (wRow0 + wm * 64 + m * 16 + lr) * 256 + g * 8;
        aPh[m] = Wch + off;
        aPl[m] = Wcl + off;
    }

    // B fragment LDS byte offsets (same XOR involution)
    unsigned lbase = (unsigned)(size_t)(lds_f16*)&smem[0][0];
    unsigned offB[4];
    #pragma unroll
    for (int n = 0; n < 4; ++n) {
        int r = wn * 64 + n * 16 + lr;
        offB[n] = (unsigned)((r * 4 + (g ^ ((r >> 1) & 3))) * 16);
    }

    f32x4 acc[4][4];
    #pragma unroll
    for (int m = 0; m < 4; ++m)
        #pragma unroll
        for (int n = 0; n < 4; ++n) acc[m][n] = (f32x4){0.f, 0.f, 0.f, 0.f};

    f16x8 aH[2][4], aL[2][4];   // A double-buffer (constexpr parity indexing)

    // prologue FIFO: s(0){NGL}, A(0){NA}, s(1){NGL}; drain s(0)+A(0),
    // keep s(1) in flight; barrier (all-waves s(0) visible).
    #pragma unroll
    for (int i = 0; i < NGL; ++i) GLDS(gB[i], &smem[0][(i * 256 + t) * 8]);
    #pragma unroll
    for (int m = 0; m < 4; ++m) {
        GLA(aH[0][m], aPh[m], 0);
        if (FULLP) GLA(aL[0][m], aPl[m], 0);
    }
    #pragma unroll
    for (int i = 0; i < NGL; ++i) GLDS(gB[i] + 32, &smem[1][(i * 256 + t) * 8]);
    wait_vmcnt<NGL>();
    __builtin_amdgcn_s_barrier();
    __builtin_amdgcn_sched_barrier(0);

#define GEMM_STEP(KS) do { \
    constexpr int ks = (KS); \
    constexpr int cur = ks & 1, nxt = (ks + 1) & 1; \
    /* B fragments from current buffer (ready: barrier at end of ks-1) */ \
    const unsigned base = lbase + (unsigned)((ks % 3) * (SLOTS * 16)); \
    f16x8 bhf[4], blf[4]; \
    _Pragma("unroll") \
    for (int n = 0; n < 4; ++n) { \
        DSR(bhf[n], base + offB[n]); \
        if (FULLP) DSR(blf[n], base + offB[n] + 8192); \
    } \
    __builtin_amdgcn_sched_barrier(0); \
    /* issue A(ks+1) into the other reg set */ \
    if constexpr (ks < 7) { \
        _Pragma("unroll") \
        for (int m = 0; m < 4; ++m) { \
            GLA(aH[nxt][m], aPh[m], (ks + 1) * 64); \
            if (FULLP) GLA(aL[nxt][m], aPl[m], (ks + 1) * 64); \
        } \
    } \
    __builtin_amdgcn_sched_barrier(0); \
    /* issue s(ks+2) staging */ \
    if constexpr (ks < 6) { \
        _Pragma("unroll") \
        for (int i = 0; i < NGL; ++i) \
            GLDS(gB[i] + (ks + 2) * 32, &smem[(ks + 2) % 3][(i * 256 + t) * 8]); \
    } \
    __builtin_amdgcn_sched_barrier(0); \
    asm volatile("s_waitcnt lgkmcnt(0)" ::: "memory"); \
    __builtin_amdgcn_sched_barrier(0); \
    /* pre-MFMA: drain A(ks); leave {s(ks+1), A(ks+1), s(ks+2)} */ \
    wait_vmcnt<(ks <= 5) ? (2 * NGL + NA) : (ks == 6 ? (NGL + NA) : 0)>(); \
    __builtin_amdgcn_sched_barrier(0); \
    _Pragma("unroll") \
    for (int n = 0; n < 4; ++n) \
        _Pragma("unroll") \
        for (int m = 0; m < 4; ++m) { \
            acc[m][n] = MFMA(aH[cur][m], bhf[n], acc[m][n]); \
            if (FULLP) { \
                acc[m][n] = MFMA(aH[cur][m], blf[n], acc[m][n]); \
                acc[m][n] = MFMA(aL[cur][m], bhf[n], acc[m][n]); \
            } \
        } \
    __builtin_amdgcn_sched_barrier(0); \
    if constexpr (ks < 7) { \
        /* post-MFMA: drain s(ks+1); leave {A(ks+1), s(ks+2)} in flight */ \
        wait_vmcnt<(ks <= 5) ? (NA + NGL) : NA>(); \
        __builtin_amdgcn_s_barrier(); \
        __builtin_amdgcn_sched_barrier(0); \
    } \
} while (0)

    GEMM_STEP(0); GEMM_STEP(1); GEMM_STEP(2); GEMM_STEP(3);
    GEMM_STEP(4); GEMM_STEP(5); GEMM_STEP(6); GEMM_STEP(7);
#undef GEMM_STEP

    // epilogue: D layout col = lane&15 (n), row = (lane>>4)*4 + reg (o)
    if (LIF) {
        #pragma unroll
        for (int m = 0; m < 4; ++m) {
            int oLoc = chOut0 + wm * 64 + m * 16 + g * 4;
            u64 rw0 = 0, rw1 = 0, rw2 = 0, rw3 = 0;
            #pragma unroll
            for (int n = 0; n < 4; ++n) {
                int nn = nT + wn * 64 + n * 16 + lr;
                #pragma unroll
                for (int r = 0; r < 4; ++r) {
                    size_t idx = ((size_t)b * C_ + oLoc + r) * N_ + nn;
                    float mm = memP[idx];
                    float v = 0.5f * mm + acc[m][n][r] - (mm > 1.0f ? 1.0f : 0.0f);
                    outP[idx] = v;
                    u64 bl = __ballot(v > 1.0f);
                    u64 fld = ((bl >> (g * 16)) & 0xFFFFull) << (n * 16);
                    if (r == 0) rw0 |= fld; else if (r == 1) rw1 |= fld;
                    else if (r == 2) rw2 |= fld; else rw3 |= fld;
                }
            }
            if (lr == 0) {
                size_t rb = ((size_t)b * 256 + oLoc) * 64 + (nt * 2 + wn);
                rowP[rb]       = rw0;
                rowP[rb + 64]  = rw1;
                rowP[rb + 128] = rw2;
                rowP[rb + 192] = rw3;
            }
        }
    } else {
        #pragma unroll
        for (int m = 0; m < 4; ++m) {
            int oLoc = chOut0 + wm * 64 + m * 16 + g * 4;
            #pragma unroll
            for (int n = 0; n < 4; ++n) {
                int nn = nT + wn * 64 + n * 16 + lr;
                #pragma unroll
                for (int r = 0; r < 4; ++r) {
                    size_t idx = ((size_t)b * C_ + oLoc + r) * N_ + nn;
                    outP[idx] = acc[m][n][r];
                }
            }
        }
    }
}

// ---------------------------------------------------------------------------
// K2 stage 1: per (bh, 8-word n-slice): partial popcounts from row masks.
// ---------------------------------------------------------------------------
__global__ __launch_bounds__(256) void kv_stage1(
    const u64* __restrict__ krow, const u64* __restrict__ vrow,
    int* __restrict__ pkv, int* __restrict__ pck, int* __restrict__ pcv)
{
    int bh = blockIdx.x, sl = blockIdx.y;
    int b = bh >> 3, h = bh & 7;
    __shared__ u64 kr[32][9], vr[32][9];
    int t = threadIdx.x;
    {
        int d = t >> 3, w = t & 7;
        size_t a = ((size_t)b * 256 + h * HD_ + d) * 64 + sl * 8 + w;
        kr[d][w] = krow[a];
        vr[d][w] = vrow[a];
    }
    __syncthreads();

    int base = bh * 8 + sl;
    if (t < 32) {
        int c = 0;
        #pragma unroll
        for (int w = 0; w < 8; ++w) c += __popcll(kr[t][w]);
        pck[base * 32 + t] = c;
    } else if (t < 64) {
        int dd = t - 32, c = 0;
        #pragma unroll
        for (int w = 0; w < 8; ++w) c += __popcll(vr[dd][w]);
        pcv[base * 32 + dd] = c;
    }
    int d = t >> 3, e0 = (t & 7) * 4;
    #pragma unroll
    for (int j = 0; j < 4; ++j) {
        int e = e0 + j, P = 0;
        #pragma unroll
        for (int w = 0; w < 8; ++w) P += __popcll(kr[d][w] & vr[e][w]);
        pkv[(size_t)base * 1024 + d * 32 + e] = P;
    }
}

// K2 stage 2: reduce 8 slices -> kvp, ksump
__global__ __launch_bounds__(256) void kv_stage2(
    const int* __restrict__ pkv, const int* __restrict__ pck,
    const int* __restrict__ pcv, float* __restrict__ kvp, float* __restrict__ ksump)
{
    int bh = blockIdx.x, t = threadIdx.x;
    __shared__ float ck[32], cv[32];
    if (t < 32) {
        int s = 0;
        #pragma unroll
        for (int sl = 0; sl < 8; ++sl) s += pck[(bh * 8 + sl) * 32 + t];
        ck[t] = (float)s;
    } else if (t < 64) {
        int dd = t - 32, s = 0;
        #pragma unroll
        for (int sl = 0; sl < 8; ++sl) s += pcv[(bh * 8 + sl) * 32 + dd];
        cv[dd] = (float)s;
    }
    __syncthreads();
    int d = t >> 3, e0 = (t & 7) * 4;
    #pragma unroll
    for (int j = 0; j < 4; ++j) {
        int e = e0 + j, P = 0;
        #pragma unroll
        for (int sl = 0; sl < 8; ++sl) P += pkv[(size_t)(bh * 8 + sl) * 1024 + d * 32 + e];
        float skv = 2.0f * (float)P - ck[d];
        float sv  = 2.0f * cv[e] - 4096.0f;
        kvp[(size_t)bh * 1024 + d * 32 + e] = ALPHA_ * sv + BETAS_ * skv;
    }
    if ((t & 7) == 0)
        ksump[bh * 32 + d] = ALPHA_ * 4096.0f + BETAS_ * ck[d];
}

// ---------------------------------------------------------------------------
// K3: att = SCALE*(q.kv)/(q.ksum+1e-6); q from row mask; out fp16 ATh [b][n][c]
// ---------------------------------------------------------------------------
__global__ __launch_bounds__(256) void att_kernel(
    const u64* __restrict__ qrow, const float* __restrict__ kvp,
    const float* __restrict__ ksump, f16* __restrict__ ATh)
{
    int bh = blockIdx.y; int b = bh >> 3, h = bh & 7;
    int n0 = blockIdx.x * 256;

    __shared__ u64 qw[32][5];
    int t = threadIdx.x;
    if (t < 128) {
        int d2 = t >> 2, w4 = t & 3;
        qw[d2][w4] = qrow[((size_t)b * 256 + h * HD_ + d2) * 64 + (n0 >> 6) + w4];
    }
    __syncthreads();

    float q[32];
    #pragma unroll
    for (int d2 = 0; d2 < 32; ++d2)
        q[d2] = ((qw[d2][t >> 6] >> (t & 63)) & 1) ? 2.0f : ALPHA_;

    const float* ksb = ksump + bh * 32;
    float den = 1e-6f;
    #pragma unroll
    for (int d2 = 0; d2 < 32; ++d2) den += q[d2] * ksb[d2];
    float rden = SCALE_ / den;

    const float* kvb = kvp + (size_t)bh * 1024;
    size_t ob = ((size_t)b * N_ + n0 + t) * C_ + h * HD_;
    #pragma unroll
    for (int qq = 0; qq < 4; ++qq) {
        f16x8 hv;
        #pragma unroll
        for (int j = 0; j < 8; ++j) {
            int e = qq * 8 + j;
            float num = 0.0f;
            #pragma unroll
            for (int d2 = 0; d2 < 32; ++d2) num += q[d2] * kvb[d2 * 32 + e];
            hv[j] = (f16)(num * rden);
        }
        *reinterpret_cast<f16x8*>(ATh + ob + qq * 8) = hv;
    }
}

// ---------------------------------------------------------------------------
// K5: BN batch stats per channel (biased var), fp64 accumulation.
// ---------------------------------------------------------------------------
__global__ __launch_bounds__(1024) void bn_stats(
    const float* __restrict__ out2, float* __restrict__ stats)
{
    int o = blockIdx.x, t = threadIdx.x;
    double s = 0.0, ss = 0.0;
    for (int b = 0; b < B_; ++b) {
        const float* p = out2 + ((size_t)b * C_ + o) * N_;
        float4 v = *reinterpret_cast<const float4*>(&p[t * 4]);
        s  += (double)v.x + (double)v.y + (double)v.z + (double)v.w;
        ss += (double)v.x * v.x + (double)v.y * v.y + (double)v.z * v.z + (double)v.w * v.w;
    }
    __shared__ double rs[1024], rss[1024];
    rs[t] = s; rss[t] = ss;
    __syncthreads();
    for (int st = 512; st > 0; st >>= 1) {
        if (t < st) { rs[t] += rs[t + st]; rss[t] += rss[t + st]; }
        __syncthreads();
    }
    if (t == 0) {
        double mean = rs[0] / 32768.0;
        double var  = rss[0] / 32768.0 - mean * mean;
        stats[o * 2 + 0] = (float)mean;
        stats[o * 2 + 1] = (float)(1.0 / sqrt(var + 1e-5));
    }
}

// K6: in-place BN apply
__global__ __launch_bounds__(256) void bn_apply(
    float* __restrict__ out, const float* __restrict__ stats,
    const float* __restrict__ gamma, const float* __restrict__ beta)
{
    size_t i = ((size_t)blockIdx.x * 256 + threadIdx.x) * 4;
    int o = (int)((i >> 12) & 255);
    float m = stats[o * 2], r = stats[o * 2 + 1];
    float g = gamma[o] * r;
    float c = beta[o] - m * g;
    float4 v = *reinterpret_cast<float4*>(&out[i]);
    v.x = v.x * g + c; v.y = v.y * g + c;
    v.z = v.z * g + c; v.w = v.w * g + c;
    *reinterpret_cast<float4*>(&out[i]) = v;
}

// ---------------------------------------------------------------------------
extern "C" void kernel_launch(void* const* d_in, const int* in_sizes, int n_in,
                              void* d_out, int out_size, void* d_ws, size_t ws_size,
                              hipStream_t stream)
{
    (void)in_sizes; (void)n_in; (void)out_size; (void)ws_size;

    const float* x     = (const float*)d_in[0];
    const float* qmem  = (const float*)d_in[1];
    const float* kmem  = (const float*)d_in[2];
    const float* vmem  = (const float*)d_in[3];
    const float* Wq    = (const float*)d_in[4];
    const float* Wk    = (const float*)d_in[5];
    const float* Wv    = (const float*)d_in[6];
    const float* Wo    = (const float*)d_in[7];
    const float* gamma = (const float*)d_in[8];
    const float* beta  = (const float*)d_in[9];

    const size_t TSZ = (size_t)B_ * C_ * N_;     // 8,388,608
    float* out0 = (float*)d_out;
    float* outq = out0 + TSZ;
    float* outk = outq + TSZ;
    float* outv = outk + TSZ;

    const size_t RSZ = (size_t)8 * 256 * 64;     // row-mask words per tensor
    char* w = (char*)d_ws;
    f16* XTh = (f16*)w;           w += TSZ * 2;
    f16* XTl = (f16*)w;           w += TSZ * 2;
    f16* ATh = (f16*)w;           w += TSZ * 2;
    f16* Wch = (f16*)w;           w += 1024 * 256 * 2;
    f16* Wcl = (f16*)w;           w += 1024 * 256 * 2;
    u64* rowm = (u64*)w;          w += 3 * RSZ * 8;
    int* pkv = (int*)w;           w += 64 * 8 * 1024 * 4;
    int* pck = (int*)w;           w += 64 * 8 * 32 * 4;
    int* pcv = (int*)w;           w += 64 * 8 * 32 * 4;
    float* kvp   = (float*)w;     w += 64 * 1024 * 4;
    float* ksump = (float*)w;     w += 64 * 32 * 4;
    float* stats = (float*)w;     w += 256 * 2 * 4;

    dim3 blk(256);

    // K0: transpose/split X, split weights
    transpose_split<<<dim3(16, 8, 8), blk, 0, stream>>>(x, XTh, XTl);
    weight_split<<<dim3(256), blk, 0, stream>>>(Wq, Wk, Wv, Wo, Wch, Wcl);

    // K1: QKV GEMM (split fp16, A-reg prefetch + counted B pipeline) + LIF
    mfma_gemm<true, true><<<dim3(1536), blk, 0, stream>>>(
        Wch, Wcl, XTh, XTl, qmem, kmem, vmem, outq, outk, outv, rowm);

    // K2: exact kv/ksum from row masks
    kv_stage1<<<dim3(64, 8), blk, 0, stream>>>(rowm + RSZ, rowm + 2 * RSZ, pkv, pck, pcv);
    kv_stage2<<<dim3(64), blk, 0, stream>>>(pkv, pck, pcv, kvp, ksump);

    // K3: attention from q mask -> fp16 ATh [b][n][c]
    att_kernel<<<dim3(16, 64), blk, 0, stream>>>(rowm, kvp, ksump, ATh);

    // K4: Wo GEMM (single-plane fp16) -> out0
    mfma_gemm<false, false><<<dim3(512), blk, 0, stream>>>(
        Wch, Wcl, ATh, ATh, nullptr, nullptr, nullptr, out0, nullptr, nullptr, nullptr);

    // K5/K6: BatchNorm
    bn_stats<<<dim3(256), dim3(1024), 0, stream>>>(out0, stats);
    bn_apply<<<dim3(8192), blk, 0, stream>>>(out0, stats, gamma, beta);
}